// Round 1
// baseline (322.737 us; speedup 1.0000x reference)
//
#include <hip/hip_runtime.h>

// GCN: 3 layers, h = relu(h + GCNConv(h)), fixed graph, f32.
// Pipeline: deg -> dis -> scan -> CSR build -> [gemm+scale, gather+relu] x NL

// ---------------- degree ----------------
__global__ void k_deg(const int* __restrict__ col, int* __restrict__ deg, int E) {
    int i = blockIdx.x * blockDim.x + threadIdx.x;
    if (i < E) atomicAdd(&deg[col[i]], 1);
}

__global__ void k_dis(const int* __restrict__ deg, float* __restrict__ dis, int n) {
    int i = blockIdx.x * blockDim.x + threadIdx.x;
    if (i < n) dis[i] = rsqrtf((float)(deg[i] + 1));  // +1 self-loop; always > 0
}

// ---------------- exclusive scan of deg (n <= 1024*CHUNK), 1 block ----------------
__global__ __launch_bounds__(1024) void k_scan(const int* __restrict__ deg,
                                               int* __restrict__ offs, int n) {
    __shared__ int part[1024];
    int t = threadIdx.x;
    int chunk = (n + 1023) >> 10;
    int base = t * chunk;
    int s = 0;
    for (int i = 0; i < chunk; ++i) {
        int idx = base + i;
        if (idx < n) s += deg[idx];
    }
    part[t] = s;
    __syncthreads();
    for (int off = 1; off < 1024; off <<= 1) {
        int v = (t >= off) ? part[t - off] : 0;
        __syncthreads();
        part[t] += v;
        __syncthreads();
    }
    int run = (t == 0) ? 0 : part[t - 1];
    for (int i = 0; i < chunk; ++i) {
        int idx = base + i;
        if (idx < n) { offs[idx] = run; run += deg[idx]; }
    }
    if (t == 1023) offs[n] = run;
}

// ---------------- CSR build (order within a node nondeterministic; fp-sum only) ----
__global__ void k_csr(const int* __restrict__ row, const int* __restrict__ col,
                      const int* __restrict__ offs, int* __restrict__ cnt,
                      int* __restrict__ csr, int E) {
    int i = blockIdx.x * blockDim.x + threadIdx.x;
    if (i < E) {
        int c = col[i];
        int p = atomicAdd(&cnt[c], 1);
        csr[offs[c] + p] = row[i];
    }
}

// ---------------- GEMM: g = (h @ W) * dis[row]  (f32 vector, 64x64 tile) ----------
__global__ __launch_bounds__(256) void k_gemm(const float* __restrict__ h,
                                              const float* __restrict__ W,
                                              const float* __restrict__ dis,
                                              float* __restrict__ g, int n) {
    __shared__ float Hl[64][132];   // +4 pad: a-reads 2-way instead of 4-way bank
    __shared__ float Wl[128][64];
    int tid = threadIdx.x;
    int rb = (blockIdx.x >> 1) * 64;
    int cb = (blockIdx.x & 1) * 64;

    {   // stage H tile: 64 rows x 128 cols
        int c4 = tid & 31, r0 = tid >> 5;  // 8 rows/pass, 512B contiguous per row
        for (int p = 0; p < 8; ++p) {
            int r = r0 + p * 8;
            float4 v = *(const float4*)&h[(size_t)(rb + r) * 128 + c4 * 4];
            *(float4*)&Hl[r][c4 * 4] = v;
        }
        // stage W tile: 128 rows x 64 cols
        int wc4 = tid & 15, k0 = tid >> 4;
        for (int p = 0; p < 8; ++p) {
            int k = k0 + p * 16;
            float4 v = *(const float4*)&W[(size_t)k * 128 + cb + wc4 * 4];
            *(float4*)&Wl[k][wc4 * 4] = v;
        }
    }
    __syncthreads();

    int jt = tid & 15, it = tid >> 4;   // wave: it spans 4 values, jt 16 -> broadcast
    float acc[4][4] = {};
    for (int k = 0; k < 128; k += 4) {
        float4 a0 = *(const float4*)&Hl[it * 4 + 0][k];
        float4 a1 = *(const float4*)&Hl[it * 4 + 1][k];
        float4 a2 = *(const float4*)&Hl[it * 4 + 2][k];
        float4 a3 = *(const float4*)&Hl[it * 4 + 3][k];
        float4 b0 = *(const float4*)&Wl[k + 0][jt * 4];
        float4 b1 = *(const float4*)&Wl[k + 1][jt * 4];
        float4 b2 = *(const float4*)&Wl[k + 2][jt * 4];
        float4 b3 = *(const float4*)&Wl[k + 3][jt * 4];
#define ROWFMA(r, ar)                                                      \
        acc[r][0] += ar.x * b0.x + ar.y * b1.x + ar.z * b2.x + ar.w * b3.x; \
        acc[r][1] += ar.x * b0.y + ar.y * b1.y + ar.z * b2.y + ar.w * b3.y; \
        acc[r][2] += ar.x * b0.z + ar.y * b1.z + ar.z * b2.z + ar.w * b3.z; \
        acc[r][3] += ar.x * b0.w + ar.y * b1.w + ar.z * b2.w + ar.w * b3.w;
        ROWFMA(0, a0) ROWFMA(1, a1) ROWFMA(2, a2) ROWFMA(3, a3)
#undef ROWFMA
    }

    for (int r = 0; r < 4; ++r) {
        int rowi = rb + it * 4 + r;
        float d = dis[rowi];
        float4 o;
        o.x = acc[r][0] * d; o.y = acc[r][1] * d;
        o.z = acc[r][2] * d; o.w = acc[r][3] * d;
        *(float4*)&g[(size_t)rowi * 128 + cb + jt * 4] = o;
    }
}

// ---------------- gather: h[c] = relu(h[c] + dis[c]*(g[c] + sum g[nbr]) + b) ------
__global__ __launch_bounds__(256) void k_gather(const float* __restrict__ g,
                                                const float* __restrict__ dis,
                                                const float* __restrict__ bias,
                                                const int* __restrict__ offs,
                                                const int* __restrict__ csr,
                                                float* __restrict__ h, int n) {
    int grp = threadIdx.x >> 5;       // 8 x 32-lane groups per block
    int lane = threadIdx.x & 31;
    int node = blockIdx.x * 8 + grp;
    if (node >= n) return;
    const float4* g4 = (const float4*)g;
    size_t nb = (size_t)node * 32 + lane;
    float4 acc = g4[nb];              // self-loop: dis[c]*g[c] after scale
    int s = offs[node], e = offs[node + 1];
    for (int j = s; j < e; ++j) {
        int r = csr[j];
        float4 v = g4[(size_t)r * 32 + lane];
        acc.x += v.x; acc.y += v.y; acc.z += v.z; acc.w += v.w;
    }
    float d = dis[node];
    float4 bv = ((const float4*)bias)[lane];
    float4 hv = ((const float4*)h)[nb];
    float4 o;
    o.x = fmaxf(hv.x + acc.x * d + bv.x, 0.f);
    o.y = fmaxf(hv.y + acc.y * d + bv.y, 0.f);
    o.z = fmaxf(hv.z + acc.z * d + bv.z, 0.f);
    o.w = fmaxf(hv.w + acc.w * d + bv.w, 0.f);
    ((float4*)h)[nb] = o;
}

extern "C" void kernel_launch(void* const* d_in, const int* in_sizes, int n_in,
                              void* d_out, int out_size, void* d_ws, size_t ws_size,
                              hipStream_t stream) {
    const float* x  = (const float*)d_in[0];
    const int*   ei = (const int*)d_in[1];
    const float* Ws = (const float*)d_in[2];
    const float* bs = (const float*)d_in[3];
    int n  = in_sizes[0] / 128;          // 32768 nodes
    int E  = in_sizes[1] / 2;            // 524288 edges
    int NL = in_sizes[2] / (128 * 128);  // 3 layers
    const int* rowp = ei;
    const int* colp = ei + E;
    float* hbuf = (float*)d_out;         // h lives in d_out across layers

    char* ws = (char*)d_ws;
    float* g   = (float*)ws;                                  // n*128 f32 = 16MB
    float* dis = (float*)(ws + (size_t)n * 128 * 4);
    int*   deg  = (int*)((char*)dis + (size_t)n * 4);
    int*   offs = (int*)((char*)deg + (size_t)n * 4);
    int*   cnt  = (int*)((char*)offs + (size_t)(n + 1) * 4);
    int*   csr  = (int*)((char*)cnt + (size_t)n * 4);         // E ints

    hipMemsetAsync(deg, 0, (size_t)n * 4, stream);
    hipMemsetAsync(cnt, 0, (size_t)n * 4, stream);
    k_deg<<<(E + 255) / 256, 256, 0, stream>>>(colp, deg, E);
    k_dis<<<(n + 255) / 256, 256, 0, stream>>>(deg, dis, n);
    k_scan<<<1, 1024, 0, stream>>>(deg, offs, n);
    k_csr<<<(E + 255) / 256, 256, 0, stream>>>(rowp, colp, offs, cnt, csr, E);
    hipMemcpyAsync(hbuf, x, (size_t)n * 128 * 4, hipMemcpyDeviceToDevice, stream);

    for (int l = 0; l < NL; ++l) {
        k_gemm<<<(n / 64) * 2, 256, 0, stream>>>(hbuf, Ws + (size_t)l * 128 * 128,
                                                 dis, g, n);
        k_gather<<<(n + 7) / 8, 256, 0, stream>>>(g, dis, bs + (size_t)l * 128,
                                                  offs, csr, hbuf, n);
    }
}

// Round 2
// 251.201 us; speedup vs baseline: 1.2848x; 1.2848x over previous
//
#include <hip/hip_runtime.h>

// GCN: 3 layers, h = relu(h + GCNConv(h)), fixed graph, f32.
// Pipeline: deg -> dis -> scan(3-pass) -> CSR build -> [gemm+scale, gather+relu] x NL

// ---------------- degree ----------------
__global__ void k_deg(const int* __restrict__ col, int* __restrict__ deg, int E) {
    int i = blockIdx.x * blockDim.x + threadIdx.x;
    if (i < E) atomicAdd(&deg[col[i]], 1);
}

__global__ void k_dis(const int* __restrict__ deg, float* __restrict__ dis, int n) {
    int i = blockIdx.x * blockDim.x + threadIdx.x;
    if (i < n) dis[i] = rsqrtf((float)(deg[i] + 1));  // +1 self-loop; always > 0
}

// ---------------- hierarchical exclusive scan: 256/block, 128 blocks ----------------
__global__ __launch_bounds__(256) void k_scan1(const int* __restrict__ deg,
                                               int* __restrict__ offs,
                                               int* __restrict__ bsum, int n) {
    __shared__ int sm[256];
    int t = threadIdx.x, i = blockIdx.x * 256 + t;
    int v = (i < n) ? deg[i] : 0;
    sm[t] = v;
    __syncthreads();
    for (int off = 1; off < 256; off <<= 1) {
        int u = (t >= off) ? sm[t - off] : 0;
        __syncthreads();
        sm[t] += u;
        __syncthreads();
    }
    if (i < n) offs[i] = sm[t] - v;           // exclusive within block
    if (t == 255) bsum[blockIdx.x] = sm[255]; // block total
}

__global__ __launch_bounds__(128) void k_scan2(int* __restrict__ bsum, int nb) {
    __shared__ int sm[128];
    int t = threadIdx.x;
    int v = (t < nb) ? bsum[t] : 0;
    sm[t] = v;
    __syncthreads();
    for (int off = 1; off < 128; off <<= 1) {
        int u = (t >= off) ? sm[t - off] : 0;
        __syncthreads();
        sm[t] += u;
        __syncthreads();
    }
    if (t < nb) bsum[t] = sm[t] - v;          // exclusive block offsets
}

__global__ __launch_bounds__(256) void k_scan3(int* __restrict__ offs,
                                               const int* __restrict__ bsum,
                                               int n, int E) {
    int i = blockIdx.x * 256 + threadIdx.x;
    if (i < n) offs[i] += bsum[blockIdx.x];
    if (i == 0) offs[n] = E;                  // sum(deg) == E
}

// ---------------- CSR build (order within a node nondeterministic; fp-sum only) ----
__global__ void k_csr(const int* __restrict__ row, const int* __restrict__ col,
                      const int* __restrict__ offs, int* __restrict__ cnt,
                      int* __restrict__ csr, int E) {
    int i = blockIdx.x * blockDim.x + threadIdx.x;
    if (i < E) {
        int c = col[i];
        int p = atomicAdd(&cnt[c], 1);
        csr[offs[c] + p] = row[i];
    }
}

// ---------------- GEMM: g = (h @ W) * dis[row]  (f32 vector, 64x64 tile) ----------
__global__ __launch_bounds__(256) void k_gemm(const float* __restrict__ h,
                                              const float* __restrict__ W,
                                              const float* __restrict__ dis,
                                              float* __restrict__ g, int n) {
    __shared__ float Hl[64][132];   // +4 pad: a-reads 2-way instead of 4-way bank
    __shared__ float Wl[128][64];
    int tid = threadIdx.x;
    int rb = (blockIdx.x >> 1) * 64;
    int cb = (blockIdx.x & 1) * 64;

    {   // stage H tile: 64 rows x 128 cols
        int c4 = tid & 31, r0 = tid >> 5;
        for (int p = 0; p < 8; ++p) {
            int r = r0 + p * 8;
            float4 v = *(const float4*)&h[(size_t)(rb + r) * 128 + c4 * 4];
            *(float4*)&Hl[r][c4 * 4] = v;
        }
        int wc4 = tid & 15, k0 = tid >> 4;
        for (int p = 0; p < 8; ++p) {
            int k = k0 + p * 16;
            float4 v = *(const float4*)&W[(size_t)k * 128 + cb + wc4 * 4];
            *(float4*)&Wl[k][wc4 * 4] = v;
        }
    }
    __syncthreads();

    int jt = tid & 15, it = tid >> 4;
    float acc[4][4] = {};
    for (int k = 0; k < 128; k += 4) {
        float4 a0 = *(const float4*)&Hl[it * 4 + 0][k];
        float4 a1 = *(const float4*)&Hl[it * 4 + 1][k];
        float4 a2 = *(const float4*)&Hl[it * 4 + 2][k];
        float4 a3 = *(const float4*)&Hl[it * 4 + 3][k];
        float4 b0 = *(const float4*)&Wl[k + 0][jt * 4];
        float4 b1 = *(const float4*)&Wl[k + 1][jt * 4];
        float4 b2 = *(const float4*)&Wl[k + 2][jt * 4];
        float4 b3 = *(const float4*)&Wl[k + 3][jt * 4];
#define ROWFMA(r, ar)                                                      \
        acc[r][0] += ar.x * b0.x + ar.y * b1.x + ar.z * b2.x + ar.w * b3.x; \
        acc[r][1] += ar.x * b0.y + ar.y * b1.y + ar.z * b2.y + ar.w * b3.y; \
        acc[r][2] += ar.x * b0.z + ar.y * b1.z + ar.z * b2.z + ar.w * b3.z; \
        acc[r][3] += ar.x * b0.w + ar.y * b1.w + ar.z * b2.w + ar.w * b3.w;
        ROWFMA(0, a0) ROWFMA(1, a1) ROWFMA(2, a2) ROWFMA(3, a3)
#undef ROWFMA
    }

    for (int r = 0; r < 4; ++r) {
        int rowi = rb + it * 4 + r;
        float d = dis[rowi];
        float4 o;
        o.x = acc[r][0] * d; o.y = acc[r][1] * d;
        o.z = acc[r][2] * d; o.w = acc[r][3] * d;
        *(float4*)&g[(size_t)rowi * 128 + cb + jt * 4] = o;
    }
}

// ---------------- gather: h[c] = relu(h[c] + dis[c]*(g[c] + sum g[nbr]) + b) ------
// One 64-lane wave per node; float2 per lane (512B/neighbor transaction).
// CSR indices loaded cooperatively (64 at a time) and broadcast via __shfl;
// neighbor loads unrolled x4 for memory-level parallelism.
__global__ __launch_bounds__(256) void k_gather(const float* __restrict__ g,
                                                const float* __restrict__ dis,
                                                const float* __restrict__ bias,
                                                const int* __restrict__ offs,
                                                const int* __restrict__ csr,
                                                float* __restrict__ h, int n) {
    int wid = threadIdx.x >> 6;
    int lane = threadIdx.x & 63;
    int node = blockIdx.x * 4 + wid;
    if (node >= n) return;
    const float2* g2 = (const float2*)g;
    size_t nb = (size_t)node * 64 + lane;
    float2 acc = g2[nb];              // self-loop term (scaled by dis[c] later)
    int s = offs[node];
    int deg = offs[node + 1] - s;
    for (int j0 = 0; j0 < deg; j0 += 64) {
        int rem = deg - j0;
        int m = rem < 64 ? rem : 64;
        int idx = (lane < m) ? csr[s + j0 + lane] : 0;
        int t = 0;
        for (; t + 4 <= m; t += 4) {
            int r0 = __shfl(idx, t, 64);
            int r1 = __shfl(idx, t + 1, 64);
            int r2 = __shfl(idx, t + 2, 64);
            int r3 = __shfl(idx, t + 3, 64);
            float2 v0 = g2[(size_t)r0 * 64 + lane];
            float2 v1 = g2[(size_t)r1 * 64 + lane];
            float2 v2 = g2[(size_t)r2 * 64 + lane];
            float2 v3 = g2[(size_t)r3 * 64 + lane];
            acc.x += (v0.x + v1.x) + (v2.x + v3.x);
            acc.y += (v0.y + v1.y) + (v2.y + v3.y);
        }
        for (; t < m; ++t) {
            int r = __shfl(idx, t, 64);
            float2 v = g2[(size_t)r * 64 + lane];
            acc.x += v.x; acc.y += v.y;
        }
    }
    float d = dis[node];
    float2 bv = ((const float2*)bias)[lane];
    float2 hv = ((const float2*)h)[nb];
    float2 o;
    o.x = fmaxf(hv.x + acc.x * d + bv.x, 0.f);
    o.y = fmaxf(hv.y + acc.y * d + bv.y, 0.f);
    ((float2*)h)[nb] = o;
}

extern "C" void kernel_launch(void* const* d_in, const int* in_sizes, int n_in,
                              void* d_out, int out_size, void* d_ws, size_t ws_size,
                              hipStream_t stream) {
    const float* x  = (const float*)d_in[0];
    const int*   ei = (const int*)d_in[1];
    const float* Ws = (const float*)d_in[2];
    const float* bs = (const float*)d_in[3];
    int n  = in_sizes[0] / 128;          // 32768 nodes
    int E  = in_sizes[1] / 2;            // 524288 edges
    int NL = in_sizes[2] / (128 * 128);  // 3 layers
    const int* rowp = ei;
    const int* colp = ei + E;
    float* hbuf = (float*)d_out;         // h lives in d_out across layers

    char* ws = (char*)d_ws;
    float* g    = (float*)ws;                                 // n*128 f32 = 16MB
    float* dis  = (float*)(ws + (size_t)n * 128 * 4);
    int*   deg  = (int*)((char*)dis + (size_t)n * 4);
    int*   offs = (int*)((char*)deg + (size_t)n * 4);
    int*   cnt  = (int*)((char*)offs + (size_t)(n + 1) * 4);
    int*   bsum = (int*)((char*)cnt + (size_t)n * 4);         // 128 ints
    int*   csr  = (int*)((char*)bsum + 512);                  // E ints

    int nb = (n + 255) / 256;            // 128 scan blocks

    hipMemsetAsync(deg, 0, (size_t)n * 4, stream);
    hipMemsetAsync(cnt, 0, (size_t)n * 4, stream);
    k_deg<<<(E + 255) / 256, 256, 0, stream>>>(colp, deg, E);
    k_dis<<<(n + 255) / 256, 256, 0, stream>>>(deg, dis, n);
    k_scan1<<<nb, 256, 0, stream>>>(deg, offs, bsum, n);
    k_scan2<<<1, 128, 0, stream>>>(bsum, nb);
    k_scan3<<<nb, 256, 0, stream>>>(offs, bsum, n, E);
    k_csr<<<(E + 255) / 256, 256, 0, stream>>>(rowp, colp, offs, cnt, csr, E);
    hipMemcpyAsync(hbuf, x, (size_t)n * 128 * 4, hipMemcpyDeviceToDevice, stream);

    for (int l = 0; l < NL; ++l) {
        k_gemm<<<(n / 64) * 2, 256, 0, stream>>>(hbuf, Ws + (size_t)l * 128 * 128,
                                                 dis, g, n);
        k_gather<<<(n + 3) / 4, 256, 0, stream>>>(g, dis, bs + (size_t)l * 128,
                                                  offs, csr, hbuf, n);
    }
}

// Round 3
// 201.177 us; speedup vs baseline: 1.6042x; 1.2487x over previous
//
#include <hip/hip_runtime.h>

// GCN: 3 layers, h = relu(h + GCNConv(h)), fixed graph, f32 in/out.
// Pipeline: deg -> dis -> scan(3-pass) -> CSR build -> [gemm(f32)->g(bf16), gather+relu] x NL
// g stored bf16: halves the random-gather traffic (268MB -> 134MB per layer).

__device__ inline ushort f2bf(float f) {           // RNE f32 -> bf16
    union { float f; unsigned u; } v; v.f = f;
    unsigned u = v.u;
    return (ushort)((u + 0x7fffu + ((u >> 16) & 1u)) >> 16);
}
__device__ inline float2 bf2f(unsigned u) {        // two packed bf16 -> float2
    union { unsigned i; float f; } a, b;
    a.i = u << 16;
    b.i = u & 0xffff0000u;
    return make_float2(a.f, b.f);
}

// ---------------- degree ----------------
__global__ void k_deg(const int* __restrict__ col, int* __restrict__ deg, int E) {
    int i = blockIdx.x * blockDim.x + threadIdx.x;
    if (i < E) atomicAdd(&deg[col[i]], 1);
}

__global__ void k_dis(const int* __restrict__ deg, float* __restrict__ dis, int n) {
    int i = blockIdx.x * blockDim.x + threadIdx.x;
    if (i < n) dis[i] = rsqrtf((float)(deg[i] + 1));  // +1 self-loop; always > 0
}

// ---------------- hierarchical exclusive scan: 256/block ----------------
__global__ __launch_bounds__(256) void k_scan1(const int* __restrict__ deg,
                                               int* __restrict__ offs,
                                               int* __restrict__ bsum, int n) {
    __shared__ int sm[256];
    int t = threadIdx.x, i = blockIdx.x * 256 + t;
    int v = (i < n) ? deg[i] : 0;
    sm[t] = v;
    __syncthreads();
    for (int off = 1; off < 256; off <<= 1) {
        int u = (t >= off) ? sm[t - off] : 0;
        __syncthreads();
        sm[t] += u;
        __syncthreads();
    }
    if (i < n) offs[i] = sm[t] - v;
    if (t == 255) bsum[blockIdx.x] = sm[255];
}

__global__ __launch_bounds__(128) void k_scan2(int* __restrict__ bsum, int nb) {
    __shared__ int sm[128];
    int t = threadIdx.x;
    int v = (t < nb) ? bsum[t] : 0;
    sm[t] = v;
    __syncthreads();
    for (int off = 1; off < 128; off <<= 1) {
        int u = (t >= off) ? sm[t - off] : 0;
        __syncthreads();
        sm[t] += u;
        __syncthreads();
    }
    if (t < nb) bsum[t] = sm[t] - v;
}

__global__ __launch_bounds__(256) void k_scan3(int* __restrict__ offs,
                                               const int* __restrict__ bsum,
                                               int n, int E) {
    int i = blockIdx.x * 256 + threadIdx.x;
    if (i < n) offs[i] += bsum[blockIdx.x];
    if (i == 0) offs[n] = E;
}

// ---------------- CSR build ----------------
__global__ void k_csr(const int* __restrict__ row, const int* __restrict__ col,
                      const int* __restrict__ offs, int* __restrict__ cnt,
                      int* __restrict__ csr, int E) {
    int i = blockIdx.x * blockDim.x + threadIdx.x;
    if (i < E) {
        int c = col[i];
        int p = atomicAdd(&cnt[c], 1);
        csr[offs[c] + p] = row[i];
    }
}

// ---------------- GEMM: g_bf16 = (h @ W) * dis[row]  (f32 vector math) ----------
__global__ __launch_bounds__(256) void k_gemm(const float* __restrict__ h,
                                              const float* __restrict__ W,
                                              const float* __restrict__ dis,
                                              ushort* __restrict__ g, int n) {
    __shared__ float Hl[64][132];
    __shared__ float Wl[128][64];
    int tid = threadIdx.x;
    int rb = (blockIdx.x >> 1) * 64;
    int cb = (blockIdx.x & 1) * 64;

    {
        int c4 = tid & 31, r0 = tid >> 5;
        for (int p = 0; p < 8; ++p) {
            int r = r0 + p * 8;
            float4 v = *(const float4*)&h[(size_t)(rb + r) * 128 + c4 * 4];
            *(float4*)&Hl[r][c4 * 4] = v;
        }
        int wc4 = tid & 15, k0 = tid >> 4;
        for (int p = 0; p < 8; ++p) {
            int k = k0 + p * 16;
            float4 v = *(const float4*)&W[(size_t)k * 128 + cb + wc4 * 4];
            *(float4*)&Wl[k][wc4 * 4] = v;
        }
    }
    __syncthreads();

    int jt = tid & 15, it = tid >> 4;
    float acc[4][4] = {};
    for (int k = 0; k < 128; k += 4) {
        float4 a0 = *(const float4*)&Hl[it * 4 + 0][k];
        float4 a1 = *(const float4*)&Hl[it * 4 + 1][k];
        float4 a2 = *(const float4*)&Hl[it * 4 + 2][k];
        float4 a3 = *(const float4*)&Hl[it * 4 + 3][k];
        float4 b0 = *(const float4*)&Wl[k + 0][jt * 4];
        float4 b1 = *(const float4*)&Wl[k + 1][jt * 4];
        float4 b2 = *(const float4*)&Wl[k + 2][jt * 4];
        float4 b3 = *(const float4*)&Wl[k + 3][jt * 4];
#define ROWFMA(r, ar)                                                      \
        acc[r][0] += ar.x * b0.x + ar.y * b1.x + ar.z * b2.x + ar.w * b3.x; \
        acc[r][1] += ar.x * b0.y + ar.y * b1.y + ar.z * b2.y + ar.w * b3.y; \
        acc[r][2] += ar.x * b0.z + ar.y * b1.z + ar.z * b2.z + ar.w * b3.z; \
        acc[r][3] += ar.x * b0.w + ar.y * b1.w + ar.z * b2.w + ar.w * b3.w;
        ROWFMA(0, a0) ROWFMA(1, a1) ROWFMA(2, a2) ROWFMA(3, a3)
#undef ROWFMA
    }

    for (int r = 0; r < 4; ++r) {
        int rowi = rb + it * 4 + r;
        float d = dis[rowi];
        ushort4 o;
        o.x = f2bf(acc[r][0] * d); o.y = f2bf(acc[r][1] * d);
        o.z = f2bf(acc[r][2] * d); o.w = f2bf(acc[r][3] * d);
        *(ushort4*)&g[(size_t)rowi * 128 + cb + jt * 4] = o;
    }
}

// ---------------- gather: hout = relu(hin + dis[c]*(g[c] + sum g[nbr]) + b) ------
// One 64-lane wave per node; g is bf16 -> one dword per lane per neighbor
// (256B/wave transaction). CSR indices broadcast via __shfl; x8 unroll for MLP.
__global__ __launch_bounds__(256) void k_gather(const ushort* __restrict__ g,
                                                const float* __restrict__ dis,
                                                const float* __restrict__ bias,
                                                const int* __restrict__ offs,
                                                const int* __restrict__ csr,
                                                const float* __restrict__ hin,
                                                float* __restrict__ hout, int n) {
    int wid = threadIdx.x >> 6;
    int lane = threadIdx.x & 63;
    int node = blockIdx.x * 4 + wid;
    if (node >= n) return;
    const unsigned* g1 = (const unsigned*)g;   // 2 bf16 per dword; row = 64 dwords
    size_t nb = (size_t)node * 64 + lane;
    float2 acc = bf2f(g1[nb]);                 // self-loop term
    int s = offs[node];
    int deg = offs[node + 1] - s;
    for (int j0 = 0; j0 < deg; j0 += 64) {
        int rem = deg - j0;
        int m = rem < 64 ? rem : 64;
        int idx = (lane < m) ? csr[s + j0 + lane] : 0;
        int t = 0;
        for (; t + 8 <= m; t += 8) {
            unsigned v0 = g1[(size_t)__shfl(idx, t + 0, 64) * 64 + lane];
            unsigned v1 = g1[(size_t)__shfl(idx, t + 1, 64) * 64 + lane];
            unsigned v2 = g1[(size_t)__shfl(idx, t + 2, 64) * 64 + lane];
            unsigned v3 = g1[(size_t)__shfl(idx, t + 3, 64) * 64 + lane];
            unsigned v4 = g1[(size_t)__shfl(idx, t + 4, 64) * 64 + lane];
            unsigned v5 = g1[(size_t)__shfl(idx, t + 5, 64) * 64 + lane];
            unsigned v6 = g1[(size_t)__shfl(idx, t + 6, 64) * 64 + lane];
            unsigned v7 = g1[(size_t)__shfl(idx, t + 7, 64) * 64 + lane];
            float2 f0 = bf2f(v0), f1 = bf2f(v1), f2 = bf2f(v2), f3 = bf2f(v3);
            float2 f4 = bf2f(v4), f5 = bf2f(v5), f6 = bf2f(v6), f7 = bf2f(v7);
            acc.x += ((f0.x + f1.x) + (f2.x + f3.x)) + ((f4.x + f5.x) + (f6.x + f7.x));
            acc.y += ((f0.y + f1.y) + (f2.y + f3.y)) + ((f4.y + f5.y) + (f6.y + f7.y));
        }
        for (; t < m; ++t) {
            float2 v = bf2f(g1[(size_t)__shfl(idx, t, 64) * 64 + lane]);
            acc.x += v.x; acc.y += v.y;
        }
    }
    float d = dis[node];
    float2 bv = ((const float2*)bias)[lane];
    float2 hv = ((const float2*)hin)[nb];
    float2 o;
    o.x = fmaxf(hv.x + acc.x * d + bv.x, 0.f);
    o.y = fmaxf(hv.y + acc.y * d + bv.y, 0.f);
    ((float2*)hout)[nb] = o;
}

extern "C" void kernel_launch(void* const* d_in, const int* in_sizes, int n_in,
                              void* d_out, int out_size, void* d_ws, size_t ws_size,
                              hipStream_t stream) {
    const float* x  = (const float*)d_in[0];
    const int*   ei = (const int*)d_in[1];
    const float* Ws = (const float*)d_in[2];
    const float* bs = (const float*)d_in[3];
    int n  = in_sizes[0] / 128;          // 32768 nodes
    int E  = in_sizes[1] / 2;            // 524288 edges
    int NL = in_sizes[2] / (128 * 128);  // 3 layers
    const int* rowp = ei;
    const int* colp = ei + E;
    float* hbuf = (float*)d_out;         // h lives in d_out across layers

    char* ws = (char*)d_ws;
    ushort* g   = (ushort*)ws;                                // n*128 bf16 = 8MB
    float* dis  = (float*)(ws + (size_t)n * 128 * 2);
    int*   deg  = (int*)((char*)dis + (size_t)n * 4);
    int*   offs = (int*)((char*)deg + (size_t)n * 4);
    int*   cnt  = (int*)((char*)offs + (size_t)(n + 1) * 4);
    int*   bsum = (int*)((char*)cnt + (size_t)n * 4);         // 128 ints
    int*   csr  = (int*)((char*)bsum + 512);                  // E ints

    int nb = (n + 255) / 256;

    hipMemsetAsync(deg, 0, (size_t)n * 4, stream);
    hipMemsetAsync(cnt, 0, (size_t)n * 4, stream);
    k_deg<<<(E + 255) / 256, 256, 0, stream>>>(colp, deg, E);
    k_dis<<<(n + 255) / 256, 256, 0, stream>>>(deg, dis, n);
    k_scan1<<<nb, 256, 0, stream>>>(deg, offs, bsum, n);
    k_scan2<<<1, 128, 0, stream>>>(bsum, nb);
    k_scan3<<<nb, 256, 0, stream>>>(offs, bsum, n, E);
    k_csr<<<(E + 255) / 256, 256, 0, stream>>>(rowp, colp, offs, cnt, csr, E);

    for (int l = 0; l < NL; ++l) {
        const float* hin = (l == 0) ? x : hbuf;
        k_gemm<<<(n / 64) * 2, 256, 0, stream>>>(hin, Ws + (size_t)l * 128 * 128,
                                                 dis, g, n);
        k_gather<<<(n + 3) / 4, 256, 0, stream>>>(g, dis, bs + (size_t)l * 128,
                                                  offs, csr, hin, hbuf, n);
    }
}

// Round 4
// 198.320 us; speedup vs baseline: 1.6274x; 1.0144x over previous
//
#include <hip/hip_runtime.h>

// GCN: 3 layers, h = relu(h + GCNConv(h)), fixed graph, f32 in/out.
// deg -> dis -> scan(3) -> CSR -> [Wt transpose, MFMA gemm -> g(bf16), gather+relu] x NL
// h kept f32 in d_out; packed-bf16 mirror hb feeds the MFMA gemm.

typedef __attribute__((ext_vector_type(8))) short short8;   // 8 bf16 = 4 VGPR
typedef __attribute__((ext_vector_type(4))) float f32x4;

__device__ inline ushort f2bf(float f) {           // RNE f32 -> bf16
    union { float f; unsigned u; } v; v.f = f;
    unsigned u = v.u;
    return (ushort)((u + 0x7fffu + ((u >> 16) & 1u)) >> 16);
}
__device__ inline float2 bf2f(unsigned u) {        // two packed bf16 -> float2
    union { unsigned i; float f; } a, b;
    a.i = u << 16;
    b.i = u & 0xffff0000u;
    return make_float2(a.f, b.f);
}

// ---------------- degree ----------------
__global__ void k_deg(const int* __restrict__ col, int* __restrict__ deg, int E) {
    int i = blockIdx.x * blockDim.x + threadIdx.x;
    if (i < E) atomicAdd(&deg[col[i]], 1);
}

__global__ void k_dis(const int* __restrict__ deg, float* __restrict__ dis, int n) {
    int i = blockIdx.x * blockDim.x + threadIdx.x;
    if (i < n) dis[i] = rsqrtf((float)(deg[i] + 1));  // +1 self-loop
}

// ---------------- hierarchical exclusive scan ----------------
__global__ __launch_bounds__(256) void k_scan1(const int* __restrict__ deg,
                                               int* __restrict__ offs,
                                               int* __restrict__ bsum, int n) {
    __shared__ int sm[256];
    int t = threadIdx.x, i = blockIdx.x * 256 + t;
    int v = (i < n) ? deg[i] : 0;
    sm[t] = v;
    __syncthreads();
    for (int off = 1; off < 256; off <<= 1) {
        int u = (t >= off) ? sm[t - off] : 0;
        __syncthreads();
        sm[t] += u;
        __syncthreads();
    }
    if (i < n) offs[i] = sm[t] - v;
    if (t == 255) bsum[blockIdx.x] = sm[255];
}

__global__ __launch_bounds__(128) void k_scan2(int* __restrict__ bsum, int nb) {
    __shared__ int sm[128];
    int t = threadIdx.x;
    int v = (t < nb) ? bsum[t] : 0;
    sm[t] = v;
    __syncthreads();
    for (int off = 1; off < 128; off <<= 1) {
        int u = (t >= off) ? sm[t - off] : 0;
        __syncthreads();
        sm[t] += u;
        __syncthreads();
    }
    if (t < nb) bsum[t] = sm[t] - v;
}

__global__ __launch_bounds__(256) void k_scan3(int* __restrict__ offs,
                                               const int* __restrict__ bsum,
                                               int n, int E) {
    int i = blockIdx.x * 256 + threadIdx.x;
    if (i < n) offs[i] += bsum[blockIdx.x];
    if (i == 0) offs[n] = E;
}

// ---------------- CSR build ----------------
__global__ void k_csr(const int* __restrict__ row, const int* __restrict__ col,
                      const int* __restrict__ offs, int* __restrict__ cnt,
                      int* __restrict__ csr, int E) {
    int i = blockIdx.x * blockDim.x + threadIdx.x;
    if (i < E) {
        int c = col[i];
        int p = atomicAdd(&cnt[c], 1);
        csr[offs[c] + p] = row[i];
    }
}

// ---------------- x (f32) -> hb (packed bf16 pairs) ----------------
__global__ void k_cvt(const float* __restrict__ x, unsigned* __restrict__ hb, int m) {
    int i = blockIdx.x * blockDim.x + threadIdx.x;
    if (i < m) {
        float2 v = ((const float2*)x)[i];
        hb[i] = ((unsigned)f2bf(v.y) << 16) | f2bf(v.x);
    }
}

// ---------------- W [k][n] f32 -> Wt [n][k] packed bf16 ----------------
__global__ __launch_bounds__(64) void k_wt(const float* __restrict__ W,
                                           unsigned* __restrict__ Wt) {
    int nn = blockIdx.x, t = threadIdx.x;
    float a = W[(size_t)(2 * t) * 128 + nn];
    float b = W[(size_t)(2 * t + 1) * 128 + nn];
    Wt[nn * 64 + t] = ((unsigned)f2bf(b) << 16) | f2bf(a);
}

// ---------------- MFMA GEMM: g = bf16((hb @ W) * dis[row]) ----------------
// 64 rows/block, 4 waves x 16 rows, full N=128 per wave. No LDS:
// A rows are block-private (no reuse), Wt is L1/L2-resident for all blocks.
__global__ __launch_bounds__(256) void k_gemm(const unsigned* __restrict__ hb,
                                              const unsigned* __restrict__ Wt,
                                              const float* __restrict__ dis,
                                              ushort* __restrict__ g, int n) {
    int w = threadIdx.x >> 6, l = threadIdx.x & 63;
    int rb = blockIdx.x * 64 + w * 16;          // wave's 16 rows
    int c = l & 15, q = l >> 4;

    // A fragments: lane holds row rb+c, k = ks*32 + q*8 .. +7  (16B chunk ks*4+q)
    const short8* arow = (const short8*)(hb + (size_t)(rb + c) * 64);
    short8 a0 = arow[0 * 4 + q], a1 = arow[1 * 4 + q];
    short8 a2 = arow[2 * 4 + q], a3 = arow[3 * 4 + q];

    f32x4 acc[8] = {};
#pragma unroll
    for (int nf = 0; nf < 8; ++nf) {
        const short8* brow = (const short8*)(Wt + (size_t)(nf * 16 + c) * 64);
        short8 b0 = brow[0 * 4 + q], b1 = brow[1 * 4 + q];
        short8 b2 = brow[2 * 4 + q], b3 = brow[3 * 4 + q];
        acc[nf] = __builtin_amdgcn_mfma_f32_16x16x32_bf16(a0, b0, acc[nf], 0, 0, 0);
        acc[nf] = __builtin_amdgcn_mfma_f32_16x16x32_bf16(a1, b1, acc[nf], 0, 0, 0);
        acc[nf] = __builtin_amdgcn_mfma_f32_16x16x32_bf16(a2, b2, acc[nf], 0, 0, 0);
        acc[nf] = __builtin_amdgcn_mfma_f32_16x16x32_bf16(a3, b3, acc[nf], 0, 0, 0);
    }

    // C/D: col = nf*16 + (l&15), row = rb + q*4 + j   [verified mapping]
    float d0 = dis[rb + q * 4 + 0], d1 = dis[rb + q * 4 + 1];
    float d2 = dis[rb + q * 4 + 2], d3 = dis[rb + q * 4 + 3];
#pragma unroll
    for (int nf = 0; nf < 8; ++nf) {
        int gc = nf * 16 + c;
        g[(size_t)(rb + q * 4 + 0) * 128 + gc] = f2bf(acc[nf][0] * d0);
        g[(size_t)(rb + q * 4 + 1) * 128 + gc] = f2bf(acc[nf][1] * d1);
        g[(size_t)(rb + q * 4 + 2) * 128 + gc] = f2bf(acc[nf][2] * d2);
        g[(size_t)(rb + q * 4 + 3) * 128 + gc] = f2bf(acc[nf][3] * d3);
    }
}

// ---------------- gather: hout = relu(hin + dis[c]*(g[c] + sum g[nbr]) + b) ------
// One wave per node; bf16 g rows -> 1 dword/lane/neighbor (256B/wave).
// Also writes packed-bf16 mirror hb for the next layer's MFMA gemm.
__global__ __launch_bounds__(256) void k_gather(const ushort* __restrict__ g,
                                                const float* __restrict__ dis,
                                                const float* __restrict__ bias,
                                                const int* __restrict__ offs,
                                                const int* __restrict__ csr,
                                                const float* __restrict__ hin,
                                                float* __restrict__ hout,
                                                unsigned* __restrict__ hb,
                                                int n, int write_hb) {
    int wid = threadIdx.x >> 6;
    int lane = threadIdx.x & 63;
    int node = blockIdx.x * 4 + wid;
    if (node >= n) return;
    const unsigned* g1 = (const unsigned*)g;   // 2 bf16/dword; row = 64 dwords
    size_t nb = (size_t)node * 64 + lane;
    float d = dis[node];
    float2 bv = ((const float2*)bias)[lane];
    float2 hv = ((const float2*)hin)[nb];
    float2 acc = bf2f(g1[nb]);                 // self-loop term
    int s = offs[node];
    int deg = offs[node + 1] - s;
    for (int j0 = 0; j0 < deg; j0 += 64) {
        int rem = deg - j0;
        int m = rem < 64 ? rem : 64;
        int idx = (lane < m) ? csr[s + j0 + lane] : 0;
        int t = 0;
        for (; t + 8 <= m; t += 8) {
            unsigned v0 = g1[(size_t)__shfl(idx, t + 0, 64) * 64 + lane];
            unsigned v1 = g1[(size_t)__shfl(idx, t + 1, 64) * 64 + lane];
            unsigned v2 = g1[(size_t)__shfl(idx, t + 2, 64) * 64 + lane];
            unsigned v3 = g1[(size_t)__shfl(idx, t + 3, 64) * 64 + lane];
            unsigned v4 = g1[(size_t)__shfl(idx, t + 4, 64) * 64 + lane];
            unsigned v5 = g1[(size_t)__shfl(idx, t + 5, 64) * 64 + lane];
            unsigned v6 = g1[(size_t)__shfl(idx, t + 6, 64) * 64 + lane];
            unsigned v7 = g1[(size_t)__shfl(idx, t + 7, 64) * 64 + lane];
            float2 f0 = bf2f(v0), f1 = bf2f(v1), f2 = bf2f(v2), f3 = bf2f(v3);
            float2 f4 = bf2f(v4), f5 = bf2f(v5), f6 = bf2f(v6), f7 = bf2f(v7);
            acc.x += ((f0.x + f1.x) + (f2.x + f3.x)) + ((f4.x + f5.x) + (f6.x + f7.x));
            acc.y += ((f0.y + f1.y) + (f2.y + f3.y)) + ((f4.y + f5.y) + (f6.y + f7.y));
        }
        for (; t < m; ++t) {
            float2 v = bf2f(g1[(size_t)__shfl(idx, t, 64) * 64 + lane]);
            acc.x += v.x; acc.y += v.y;
        }
    }
    float2 o;
    o.x = fmaxf(hv.x + acc.x * d + bv.x, 0.f);
    o.y = fmaxf(hv.y + acc.y * d + bv.y, 0.f);
    ((float2*)hout)[nb] = o;
    if (write_hb)
        hb[nb] = ((unsigned)f2bf(o.y) << 16) | f2bf(o.x);
}

extern "C" void kernel_launch(void* const* d_in, const int* in_sizes, int n_in,
                              void* d_out, int out_size, void* d_ws, size_t ws_size,
                              hipStream_t stream) {
    const float* x  = (const float*)d_in[0];
    const int*   ei = (const int*)d_in[1];
    const float* Ws = (const float*)d_in[2];
    const float* bs = (const float*)d_in[3];
    int n  = in_sizes[0] / 128;          // 32768 nodes
    int E  = in_sizes[1] / 2;            // 524288 edges
    int NL = in_sizes[2] / (128 * 128);  // 3 layers
    const int* rowp = ei;
    const int* colp = ei + E;
    float* hbuf = (float*)d_out;

    char* ws = (char*)d_ws;
    ushort*   gq  = (ushort*)ws;                               // n*128 bf16 = 8MB
    unsigned* hb  = (unsigned*)(ws + (size_t)n * 128 * 2);     // n*64 dw  = 8MB
    unsigned* Wt  = (unsigned*)((char*)hb + (size_t)n * 64 * 4);  // 32KB
    float* dis  = (float*)((char*)Wt + 128 * 64 * 4);
    int*   deg  = (int*)((char*)dis + (size_t)n * 4);
    int*   offs = (int*)((char*)deg + (size_t)n * 4);
    int*   cnt  = (int*)((char*)offs + (size_t)(n + 1) * 4);
    int*   bsum = (int*)((char*)cnt + (size_t)n * 4);          // 128 ints
    int*   csr  = (int*)((char*)bsum + 512);                   // E ints

    int nb = (n + 255) / 256;

    hipMemsetAsync(deg, 0, (size_t)n * 4, stream);
    hipMemsetAsync(cnt, 0, (size_t)n * 4, stream);
    k_deg<<<(E + 255) / 256, 256, 0, stream>>>(colp, deg, E);
    k_dis<<<(n + 255) / 256, 256, 0, stream>>>(deg, dis, n);
    k_scan1<<<nb, 256, 0, stream>>>(deg, offs, bsum, n);
    k_scan2<<<1, 128, 0, stream>>>(bsum, nb);
    k_scan3<<<nb, 256, 0, stream>>>(offs, bsum, n, E);
    k_csr<<<(E + 255) / 256, 256, 0, stream>>>(rowp, colp, offs, cnt, csr, E);
    k_cvt<<<(n * 64 + 255) / 256, 256, 0, stream>>>(x, hb, n * 64);

    for (int l = 0; l < NL; ++l) {
        const float* hin = (l == 0) ? x : hbuf;
        k_wt<<<128, 64, 0, stream>>>(Ws + (size_t)l * 128 * 128, Wt);
        k_gemm<<<n / 64, 256, 0, stream>>>(hb, Wt, dis, gq, n);
        k_gather<<<(n + 3) / 4, 256, 0, stream>>>(gq, dis, bs + (size_t)l * 128,
                                                  offs, csr, hin, hbuf, hb, n,
                                                  l + 1 < NL);
    }
}